// Round 1
// baseline (2369.720 us; speedup 1.0000x reference)
//
#include <hip/hip_runtime.h>
#include <hip/hip_bf16.h>
#include <stdint.h>

typedef __bf16 bf16x8 __attribute__((ext_vector_type(8)));
typedef float  f32x4  __attribute__((ext_vector_type(4)));

#define NH      4096
#define MB      1024
#define M2      2048
#define DIN     784
#define KPAD    832      /* 13*64 */
#define N_IN    8192
#define NLAYERS 24
#define NOUT    10

__device__ __forceinline__ unsigned short f2bf(float x) {
  union { float f; unsigned u; } v; v.f = x;
  unsigned r = v.u + 0x7FFFu + ((v.u >> 16) & 1u);   // RNE (finite inputs)
  return (unsigned short)(r >> 16);
}
__device__ __forceinline__ float bf2f(unsigned short u) {
  union { unsigned u; float f; } v; v.u = ((unsigned)u) << 16; return v.f;
}

__device__ __forceinline__ void async16(const void* g, void* l) {
  __builtin_amdgcn_global_load_lds(
      (const __attribute__((address_space(1))) void*)g,
      (__attribute__((address_space(3))) void*)l, 16, 0, 0);
}

// ---------- weight/input conversion ----------
__global__ void k_conv_wsp(const float* __restrict__ W, const float* __restrict__ o,
                           unsigned short* __restrict__ out) {
  size_t i = ((size_t)blockIdx.x * blockDim.x + threadIdx.x) * 4;
  if (i >= (size_t)NH * NH) return;
  float4 w = *reinterpret_cast<const float4*>(W + i);
  int k = (int)(i & (NH - 1));
  float4 ov = *reinterpret_cast<const float4*>(o + k);
  ushort4 r;
  r.x = f2bf(w.x * ov.x); r.y = f2bf(w.y * ov.y);
  r.z = f2bf(w.z * ov.z); r.w = f2bf(w.w * ov.w);
  *reinterpret_cast<ushort4*>(out + i) = r;
}

__global__ void k_conv_pad(const float* __restrict__ in, unsigned short* __restrict__ out,
                           int rows, int kin, int kout) {
  size_t i = (size_t)blockIdx.x * blockDim.x + threadIdx.x;
  if (i >= (size_t)rows * kout) return;
  int r = (int)(i / kout), c = (int)(i % kout);
  out[i] = (c < kin) ? f2bf(in[(size_t)r * kin + c]) : (unsigned short)0;
}

// ---------- shared GEMM main loop (128x128 tile, BK=64, 4 waves) ----------
__device__ __forceinline__ void gemm_tile(
    const unsigned short* __restrict__ A, const unsigned short* __restrict__ B,
    int K, int bm, int bn, unsigned short* sA, unsigned short* sB,
    f32x4 acc[4][4])
{
  const int t    = threadIdx.x;
  const int lane = t & 63;
  const int l15  = lane & 15;
  const int lk8  = (lane >> 4) * 8;
  const int wave = t >> 6;
  const int wm   = (wave >> 1) * 64;
  const int wn   = (wave & 1) * 64;

  for (int k0 = 0; k0 < K; k0 += 64) {
#pragma unroll
    for (int i = 0; i < 4; ++i) {
      const int c   = i * 256 + t;
      const int row = c >> 3;          // 8 chunks of 16B per 64-wide row
      const int col = (c & 7) * 8;
      async16(A + (size_t)(bm + row) * K + (k0 + col), sA + c * 8);
      async16(B + (size_t)(bn + row) * K + (k0 + col), sB + c * 8);
    }
    __syncthreads();   // compiler emits s_waitcnt vmcnt(0) before s_barrier
#pragma unroll
    for (int kk = 0; kk < 2; ++kk) {
      bf16x8 af[4], bfr[4];
#pragma unroll
      for (int mi = 0; mi < 4; ++mi)
        af[mi] = *reinterpret_cast<const bf16x8*>(sA + (wm + mi * 16 + l15) * 64 + kk * 32 + lk8);
#pragma unroll
      for (int ni = 0; ni < 4; ++ni)
        bfr[ni] = *reinterpret_cast<const bf16x8*>(sB + (wn + ni * 16 + l15) * 64 + kk * 32 + lk8);
#pragma unroll
      for (int mi = 0; mi < 4; ++mi)
#pragma unroll
        for (int ni = 0; ni < 4; ++ni)
          acc[mi][ni] = __builtin_amdgcn_mfma_f32_16x16x32_bf16(af[mi], bfr[ni], acc[mi][ni], 0, 0, 0);
    }
    __syncthreads();
  }
}

// ---------- recurrent layer GEMM: Y = A @ Wsp'.T + b ; preact + relu->bf16 ----------
__global__ __launch_bounds__(256, 2) void k_gemm_layer(
    const unsigned short* __restrict__ A, const unsigned short* __restrict__ W,
    const float* __restrict__ bias, float* __restrict__ preact,
    unsigned short* __restrict__ Anext)
{
  __shared__ __align__(16) unsigned short sA[128 * 64];
  __shared__ __align__(16) unsigned short sB[128 * 64];
  const int bm = blockIdx.y * 128, bn = blockIdx.x * 128;
  f32x4 acc[4][4] = {};
  gemm_tile(A, W, NH, bm, bn, sA, sB, acc);

  const int lane = threadIdx.x & 63;
  const int wave = threadIdx.x >> 6;
  const int wm = (wave >> 1) * 64, wn = (wave & 1) * 64;
  const int l15 = lane & 15;
#pragma unroll
  for (int mi = 0; mi < 4; ++mi) {
    const int gm0 = bm + wm + mi * 16 + (lane >> 4) * 4;   // C/D: row=(lane>>4)*4+r
#pragma unroll
    for (int ni = 0; ni < 4; ++ni) {
      const int gn = bn + wn + ni * 16 + l15;              // C/D: col=lane&15
      const float bv = bias[gn];
#pragma unroll
      for (int r = 0; r < 4; ++r) {
        const int gm = gm0 + r;
        const float y = acc[mi][ni][r] + bv;
        if (gm < MB) preact[(size_t)gm * NH + gn] = y;     // ya pre-activation
        Anext[(size_t)gm * NH + gn] = f2bf(y > 0.f ? y : 0.f);
      }
    }
  }
}

// ---------- input GEMM: r = x @ W_in.T + b_in ; split a/b, preact0, relu ----------
__global__ __launch_bounds__(256, 2) void k_gemm_in(
    const unsigned short* __restrict__ X, const unsigned short* __restrict__ W,
    const float* __restrict__ bias, float* __restrict__ preact0,
    unsigned short* __restrict__ A0)
{
  __shared__ __align__(16) unsigned short sA[128 * 64];
  __shared__ __align__(16) unsigned short sB[128 * 64];
  const int bm = blockIdx.y * 128, bn = blockIdx.x * 128;
  f32x4 acc[4][4] = {};
  gemm_tile(X, W, KPAD, bm, bn, sA, sB, acc);

  const int lane = threadIdx.x & 63;
  const int wave = threadIdx.x >> 6;
  const int wm = (wave >> 1) * 64, wn = (wave & 1) * 64;
  const int l15 = lane & 15;
#pragma unroll
  for (int mi = 0; mi < 4; ++mi) {
    const int gm0 = bm + wm + mi * 16 + (lane >> 4) * 4;
#pragma unroll
    for (int ni = 0; ni < 4; ++ni) {
      const int gn = bn + wn + ni * 16 + l15;
      const float bv = bias[gn];
#pragma unroll
      for (int r = 0; r < 4; ++r) {
        const int gm = gm0 + r;
        const float y = acc[mi][ni][r] + bv;
        const unsigned short rl = f2bf(y > 0.f ? y : 0.f);
        if (gn < NH) {                       // "a" stream
          preact0[(size_t)gm * NH + gn] = y;
          A0[(size_t)gm * NH + gn] = rl;
        } else {                             // "b" stream -> rows 1024..2047
          A0[(size_t)(MB + gm) * NH + (gn - NH)] = rl;
        }
      }
    }
  }
}

// ---------- final head: out = (A * of) @ W_f.T + b_f  (N=10) ----------
__global__ void k_final(const unsigned short* __restrict__ A,
                        const float* __restrict__ Wf, const float* __restrict__ of,
                        const float* __restrict__ bf_, float* __restrict__ out)
{
  const int m = blockIdx.x;        // 0..2047
  const int t = threadIdx.x;       // 256
  float accj[NOUT] = {};
  for (int k = t; k < NH; k += 256) {
    const float a = bf2f(A[(size_t)m * NH + k]) * of[k];
#pragma unroll
    for (int j = 0; j < NOUT; ++j) accj[j] += a * Wf[j * NH + k];
  }
  __shared__ float red[4][NOUT];
#pragma unroll
  for (int j = 0; j < NOUT; ++j) {
    float v = accj[j];
    for (int off = 32; off > 0; off >>= 1) v += __shfl_down(v, off);
    if ((t & 63) == 0) red[t >> 6][j] = v;
  }
  __syncthreads();
  if (t < NOUT) {
    const float s = red[0][t] + red[1][t] + red[2][t] + red[3][t] + bf_[t];
    const size_t o = (m < MB) ? ((size_t)m * NOUT + t)
                              : ((size_t)MB * NOUT + (size_t)(m - MB) * NOUT + t);
    out[o] = s;
  }
}

extern "C" void kernel_launch(void* const* d_in, const int* in_sizes, int n_in,
                              void* d_out, int out_size, void* d_ws, size_t ws_size,
                              hipStream_t stream) {
  const float* x     = (const float*)d_in[0];
  const float* W_in  = (const float*)d_in[1];
  const float* b_in  = (const float*)d_in[2];
  const float* keysp = (const float*)d_in[3];   // (1,4096) -> row 0 (time%1==0)
  const float* W_sp  = (const float*)d_in[4];
  const float* b_sp  = (const float*)d_in[5];
  const float* keyf  = (const float*)d_in[6];
  const float* W_f   = (const float*)d_in[7];
  const float* b_f   = (const float*)d_in[8];
  // d_in[9] = time, ignored (key arrays have 1 row)

  float* out    = (float*)d_out;
  float* preact = out + (size_t)2 * MB * NOUT;  // 25 x 1024 x 4096

  char* ws = (char*)d_ws;
  unsigned short* Wsp_bf = (unsigned short*)ws;  ws += (size_t)NH * NH * 2;
  unsigned short* A0     = (unsigned short*)ws;  ws += (size_t)M2 * NH * 2;
  unsigned short* A1     = (unsigned short*)ws;  ws += (size_t)M2 * NH * 2;
  unsigned short* Win_bf = (unsigned short*)ws;  ws += (size_t)N_IN * KPAD * 2;
  unsigned short* X_bf   = (unsigned short*)ws;  ws += (size_t)MB * KPAD * 2;

  // 1) fold o into W_sp, convert weights/inputs to bf16 (K padded to 832)
  k_conv_wsp<<<(NH * (size_t)NH / 4 + 255) / 256, 256, 0, stream>>>(W_sp, keysp, Wsp_bf);
  k_conv_pad<<<((size_t)N_IN * KPAD + 255) / 256, 256, 0, stream>>>(W_in, Win_bf, N_IN, DIN, KPAD);
  k_conv_pad<<<((size_t)MB * KPAD + 255) / 256, 256, 0, stream>>>(x, X_bf, MB, DIN, KPAD);

  // 2) input GEMM: 1024 x 8192, K=832
  k_gemm_in<<<dim3(N_IN / 128, MB / 128), 256, 0, stream>>>(X_bf, Win_bf, b_in, preact, A0);

  // 3) 24 recurrent layers: 2048 x 4096, K=4096
  unsigned short* Ain = A0;
  unsigned short* Aout = A1;
  for (int tlay = 0; tlay < NLAYERS; ++tlay) {
    float* pre = preact + (size_t)(tlay + 1) * MB * NH;
    k_gemm_layer<<<dim3(NH / 128, M2 / 128), 256, 0, stream>>>(Ain, Wsp_bf, b_sp, pre, Aout);
    unsigned short* tmp = Ain; Ain = Aout; Aout = tmp;
  }

  // 4) head (reads Ain = final activations)
  k_final<<<M2, 256, 0, stream>>>(Ain, W_f, keyf, b_f, out);
}

// Round 2
// 1794.344 us; speedup vs baseline: 1.3207x; 1.3207x over previous
//
#include <hip/hip_runtime.h>
#include <hip/hip_bf16.h>
#include <stdint.h>

typedef __bf16 bf16x8 __attribute__((ext_vector_type(8)));
typedef float  f32x4  __attribute__((ext_vector_type(4)));

#define NH      4096
#define MB      1024
#define M2      2048
#define DIN     784
#define KPAD    832      /* 13*64 */
#define N_IN    8192
#define NLAYERS 24
#define NOUT    10

// GEMM geometry: 256x128 tile, BK=64, 512 threads = 8 waves (4M x 2N), 64x64/wave
#define ABUF    8192                 /* elements per A K-half subtile [256][32] */
#define BBUF    4096                 /* elements per B K-half subtile [128][32] */
#define BUFSTR  (2*ABUF + 2*BBUF)    /* 24576 elements = 48 KB per buffer */

__device__ __forceinline__ unsigned short f2bf(float x) {
  union { float f; unsigned u; } v; v.f = x;
  unsigned r = v.u + 0x7FFFu + ((v.u >> 16) & 1u);   // RNE (finite inputs)
  return (unsigned short)(r >> 16);
}
__device__ __forceinline__ float bf2f(unsigned short u) {
  union { unsigned u; float f; } v; v.u = ((unsigned)u) << 16; return v.f;
}

__device__ __forceinline__ void async16(const void* g, void* l) {
  __builtin_amdgcn_global_load_lds(
      (const __attribute__((address_space(1))) void*)g,
      (__attribute__((address_space(3))) void*)l, 16, 0, 0);
}

// ---------- weight/input conversion ----------
__global__ void k_conv_wsp(const float* __restrict__ W, const float* __restrict__ o,
                           unsigned short* __restrict__ out) {
  size_t i = ((size_t)blockIdx.x * blockDim.x + threadIdx.x) * 4;
  if (i >= (size_t)NH * NH) return;
  float4 w = *reinterpret_cast<const float4*>(W + i);
  int k = (int)(i & (NH - 1));
  float4 ov = *reinterpret_cast<const float4*>(o + k);
  ushort4 r;
  r.x = f2bf(w.x * ov.x); r.y = f2bf(w.y * ov.y);
  r.z = f2bf(w.z * ov.z); r.w = f2bf(w.w * ov.w);
  *reinterpret_cast<ushort4*>(out + i) = r;
}

__global__ void k_conv_pad(const float* __restrict__ in, unsigned short* __restrict__ out,
                           int rows, int kin, int kout) {
  size_t i = (size_t)blockIdx.x * blockDim.x + threadIdx.x;
  if (i >= (size_t)rows * kout) return;
  int r = (int)(i / kout), c = (int)(i % kout);
  out[i] = (c < kin) ? f2bf(in[(size_t)r * kin + c]) : (unsigned short)0;
}

// ---------- pipelined GEMM core: counted-vmcnt, swizzled LDS, 2 sub-phases/K-tile ----------
// acc[mi][ni] covers wave tile 64x64 at (wm*64, wn*64) within the 256x128 block tile.
__device__ __forceinline__ void gemm_core(
    const unsigned short* __restrict__ Ag, const unsigned short* __restrict__ Bg,
    int K, int bm, int bn, unsigned short* lds, f32x4 acc[4][4])
{
  const int t    = threadIdx.x;
  const int lane = t & 63;
  const int wave = t >> 6;
  const int wm   = wave >> 1;          // 0..3 -> 64-row band
  const int wn   = wave & 1;           // 0..1 -> 64-col band
  const int l15  = lane & 15;
  const int lk8  = (lane >> 4) * 8;    // k-offset within K-half

  // ---- staging precompute (linear LDS dest, pre-swizzled global source) ----
  unsigned aOffG[2]; int aOffL[2];
#pragma unroll
  for (int j = 0; j < 2; ++j) {
    const int d   = (j * 512 + t) * 16;            // byte offset in A [256][32] subtile
    const int row = d >> 6;
    const int l   = d ^ (((row >> 1) & 3) << 4);   // involutive swizzle
    aOffL[j] = d >> 1;                             // element offset (linear dest)
    aOffG[j] = (unsigned)((bm + row) * K + ((l & 63) >> 1));
  }
  unsigned bOffG; int bOffL;
  {
    const int d   = t * 16;                        // byte offset in B [128][32] subtile
    const int row = d >> 6;
    const int l   = d ^ (((row >> 1) & 3) << 4);
    bOffL = d >> 1;
    bOffG = (unsigned)((bn + row) * K + ((l & 63) >> 1));
  }

  // ---- fragment read offsets (elements within subtile, swizzled) ----
  int aRd[4], bRd[4];
#pragma unroll
  for (int i = 0; i < 4; ++i) {
    const int ra = wm * 64 + i * 16 + l15;
    aRd[i] = ((ra * 64 + lk8 * 2) ^ (((ra >> 1) & 3) << 4)) >> 1;
    const int rb = wn * 64 + i * 16 + l15;
    bRd[i] = ((rb * 64 + lk8 * 2) ^ (((rb >> 1) & 3) << 4)) >> 1;
  }

  auto STAGE = [&](int bufE, int k0, int kh) {
    const int khA = bufE + kh * ABUF;
    const int khB = bufE + 2 * ABUF + kh * BBUF;
    const unsigned kadd = (unsigned)(k0 + kh * 32);
    async16(Ag + aOffG[0] + kadd, lds + khA + aOffL[0]);
    async16(Ag + aOffG[1] + kadd, lds + khA + aOffL[1]);
    async16(Bg + bOffG    + kadd, lds + khB + bOffL);
  };

  auto SUBPHASE = [&](int cur, int kk, int nxt, int k0n, bool st, bool last) {
    if (last) asm volatile("s_waitcnt vmcnt(0)" ::: "memory");
    else      asm volatile("s_waitcnt vmcnt(3)" ::: "memory");
    __builtin_amdgcn_s_barrier();
    __builtin_amdgcn_sched_barrier(0);
    if (st) STAGE(nxt, k0n, kk);               // prefetch next K-tile's K-half kk
    const int kkA = cur + kk * ABUF;
    const int kkB = cur + 2 * ABUF + kk * BBUF;
    bf16x8 af[4], bv[4];
#pragma unroll
    for (int i = 0; i < 4; ++i) af[i] = *reinterpret_cast<const bf16x8*>(lds + kkA + aRd[i]);
#pragma unroll
    for (int i = 0; i < 4; ++i) bv[i] = *reinterpret_cast<const bf16x8*>(lds + kkB + bRd[i]);
    asm volatile("s_waitcnt lgkmcnt(0)" ::: "memory");
    __builtin_amdgcn_sched_barrier(0);
    __builtin_amdgcn_s_setprio(1);
#pragma unroll
    for (int mi = 0; mi < 4; ++mi)
#pragma unroll
      for (int ni = 0; ni < 4; ++ni)
        acc[mi][ni] = __builtin_amdgcn_mfma_f32_16x16x32_bf16(af[mi], bv[ni], acc[mi][ni], 0, 0, 0);
    __builtin_amdgcn_s_setprio(0);
    __builtin_amdgcn_sched_barrier(0);
  };

  // prologue: stage K-tile 0 (both halves) into buffer 0 -> 6 loads in flight
  STAGE(0, 0, 0);
  STAGE(0, 0, 1);
  const int nt = K >> 6;
  for (int kt = 0; kt < nt; ++kt) {
    const int cur = (kt & 1) ? BUFSTR : 0;
    const int nxt = cur ^ BUFSTR;
    const bool st = (kt + 1 < nt);
    SUBPHASE(cur, 0, nxt, (kt + 1) << 6, st, false);
    SUBPHASE(cur, 1, nxt, (kt + 1) << 6, st, !st);
  }
}

// ---------- recurrent layer GEMM: Y = A @ Wsp'.T + b ; preact + relu->bf16 ----------
__global__ __launch_bounds__(512, 2) void k_gemm_layer(
    const unsigned short* __restrict__ A, const unsigned short* __restrict__ W,
    const float* __restrict__ bias, float* __restrict__ preact,
    unsigned short* __restrict__ Anext)
{
  __shared__ __align__(16) unsigned short lds[2 * BUFSTR];   // 96 KB
  const int bid = blockIdx.x;                  // 256 blocks
  const int s   = ((bid & 7) << 5) + (bid >> 3);   // XCD-aware bijective swizzle
  const int bm = (s >> 5) * 256;               // NH/128 = 32 n-blocks
  const int bn = (s & 31) * 128;
  f32x4 acc[4][4] = {};
  gemm_core(A, W, NH, bm, bn, lds, acc);

  const int lane = threadIdx.x & 63;
  const int wave = threadIdx.x >> 6;
  const int wm = (wave >> 1) * 64, wn = (wave & 1) * 64;
  const int l15 = lane & 15;
#pragma unroll
  for (int mi = 0; mi < 4; ++mi) {
    const int gm0 = bm + wm + mi * 16 + (lane >> 4) * 4;
#pragma unroll
    for (int ni = 0; ni < 4; ++ni) {
      const int gn = bn + wn + ni * 16 + l15;
      const float bv = bias[gn];
#pragma unroll
      for (int r = 0; r < 4; ++r) {
        const int gm = gm0 + r;
        const float y = acc[mi][ni][r] + bv;
        if (gm < MB) preact[(size_t)gm * NH + gn] = y;
        Anext[(size_t)gm * NH + gn] = f2bf(y > 0.f ? y : 0.f);
      }
    }
  }
}

// ---------- input GEMM: r = x @ W_in.T + b_in ; split a/b, preact0, relu ----------
__global__ __launch_bounds__(512, 2) void k_gemm_in(
    const unsigned short* __restrict__ X, const unsigned short* __restrict__ W,
    const float* __restrict__ bias, float* __restrict__ preact0,
    unsigned short* __restrict__ A0)
{
  __shared__ __align__(16) unsigned short lds[2 * BUFSTR];
  const int bid = blockIdx.x;                  // 256 blocks
  const int s   = ((bid & 7) << 5) + (bid >> 3);
  const int bm = (s >> 6) * 256;               // N_IN/128 = 64 n-blocks
  const int bn = (s & 63) * 128;
  f32x4 acc[4][4] = {};
  gemm_core(X, W, KPAD, bm, bn, lds, acc);

  const int lane = threadIdx.x & 63;
  const int wave = threadIdx.x >> 6;
  const int wm = (wave >> 1) * 64, wn = (wave & 1) * 64;
  const int l15 = lane & 15;
#pragma unroll
  for (int mi = 0; mi < 4; ++mi) {
    const int gm0 = bm + wm + mi * 16 + (lane >> 4) * 4;
#pragma unroll
    for (int ni = 0; ni < 4; ++ni) {
      const int gn = bn + wn + ni * 16 + l15;
      const float bv = bias[gn];
#pragma unroll
      for (int r = 0; r < 4; ++r) {
        const int gm = gm0 + r;
        const float y = acc[mi][ni][r] + bv;
        const unsigned short rl = f2bf(y > 0.f ? y : 0.f);
        if (gn < NH) {                       // "a" stream
          preact0[(size_t)gm * NH + gn] = y;
          A0[(size_t)gm * NH + gn] = rl;
        } else {                             // "b" stream -> rows 1024..2047
          A0[(size_t)(MB + gm) * NH + (gn - NH)] = rl;
        }
      }
    }
  }
}

// ---------- final head: out = (A * of) @ W_f.T + b_f  (N=10) ----------
__global__ void k_final(const unsigned short* __restrict__ A,
                        const float* __restrict__ Wf, const float* __restrict__ of,
                        const float* __restrict__ bf_, float* __restrict__ out)
{
  const int m = blockIdx.x;        // 0..2047
  const int t = threadIdx.x;       // 256
  float accj[NOUT] = {};
  for (int k = t; k < NH; k += 256) {
    const float a = bf2f(A[(size_t)m * NH + k]) * of[k];
#pragma unroll
    for (int j = 0; j < NOUT; ++j) accj[j] += a * Wf[j * NH + k];
  }
  __shared__ float red[4][NOUT];
#pragma unroll
  for (int j = 0; j < NOUT; ++j) {
    float v = accj[j];
    for (int off = 32; off > 0; off >>= 1) v += __shfl_down(v, off);
    if ((t & 63) == 0) red[t >> 6][j] = v;
  }
  __syncthreads();
  if (t < NOUT) {
    const float s = red[0][t] + red[1][t] + red[2][t] + red[3][t] + bf_[t];
    out[(size_t)m * NOUT + t] = s;
  }
}

extern "C" void kernel_launch(void* const* d_in, const int* in_sizes, int n_in,
                              void* d_out, int out_size, void* d_ws, size_t ws_size,
                              hipStream_t stream) {
  const float* x     = (const float*)d_in[0];
  const float* W_in  = (const float*)d_in[1];
  const float* b_in  = (const float*)d_in[2];
  const float* keysp = (const float*)d_in[3];
  const float* W_sp  = (const float*)d_in[4];
  const float* b_sp  = (const float*)d_in[5];
  const float* keyf  = (const float*)d_in[6];
  const float* W_f   = (const float*)d_in[7];
  const float* b_f   = (const float*)d_in[8];

  float* out    = (float*)d_out;
  float* preact = out + (size_t)2 * MB * NOUT;  // 25 x 1024 x 4096

  char* ws = (char*)d_ws;
  unsigned short* Wsp_bf = (unsigned short*)ws;  ws += (size_t)NH * NH * 2;
  unsigned short* A0     = (unsigned short*)ws;  ws += (size_t)M2 * NH * 2;
  unsigned short* A1     = (unsigned short*)ws;  ws += (size_t)M2 * NH * 2;
  unsigned short* Win_bf = (unsigned short*)ws;  ws += (size_t)N_IN * KPAD * 2;
  unsigned short* X_bf   = (unsigned short*)ws;  ws += (size_t)MB * KPAD * 2;

  k_conv_wsp<<<(NH * (size_t)NH / 4 + 255) / 256, 256, 0, stream>>>(W_sp, keysp, Wsp_bf);
  k_conv_pad<<<((size_t)N_IN * KPAD + 255) / 256, 256, 0, stream>>>(W_in, Win_bf, N_IN, DIN, KPAD);
  k_conv_pad<<<((size_t)MB * KPAD + 255) / 256, 256, 0, stream>>>(x, X_bf, MB, DIN, KPAD);

  // input GEMM: M=1024, N=8192, K=832 -> 4*64 = 256 blocks
  k_gemm_in<<<256, 512, 0, stream>>>(X_bf, Win_bf, b_in, preact, A0);

  // 24 recurrent layers: M=2048, N=4096, K=4096 -> 8*32 = 256 blocks
  unsigned short* Ain = A0;
  unsigned short* Aout = A1;
  for (int tlay = 0; tlay < NLAYERS; ++tlay) {
    float* pre = preact + (size_t)(tlay + 1) * MB * NH;
    k_gemm_layer<<<256, 512, 0, stream>>>(Ain, Wsp_bf, b_sp, pre, Aout);
    unsigned short* tmp = Ain; Ain = Aout; Aout = tmp;
  }

  k_final<<<M2, 256, 0, stream>>>(Ain, W_f, keyf, b_f, out);
}

// Round 3
// 1758.076 us; speedup vs baseline: 1.3479x; 1.0206x over previous
//
#include <hip/hip_runtime.h>
#include <hip/hip_bf16.h>
#include <stdint.h>

typedef __bf16 bf16x8 __attribute__((ext_vector_type(8)));
typedef float  f32x4  __attribute__((ext_vector_type(4)));

#define NH      4096
#define MB      1024
#define M2      2048
#define DIN     784
#define KPAD    832      /* 13*64 */
#define N_IN    8192
#define NLAYERS 24
#define NOUT    10

// GEMM geometry: 256x128 tile, BK=64, 512 threads = 8 waves (4M x 2N), 64x64/wave.
// LDS: 3-slot ring, slot = A[256][64] + B[128][64] bf16 (48 KB), total 144 KB.
#define ASLOT   (256 * 64)            /* elements */
#define BSLOT   (128 * 64)
#define SLOT    (ASLOT + BSLOT)       /* 24576 elements = 48 KB */

__device__ __forceinline__ unsigned short f2bf(float x) {
  union { float f; unsigned u; } v; v.f = x;
  unsigned r = v.u + 0x7FFFu + ((v.u >> 16) & 1u);   // RNE (finite inputs)
  return (unsigned short)(r >> 16);
}
__device__ __forceinline__ float bf2f(unsigned short u) {
  union { unsigned u; float f; } v; v.u = ((unsigned)u) << 16; return v.f;
}

__device__ __forceinline__ void async16(const void* g, void* l) {
  __builtin_amdgcn_global_load_lds(
      (const __attribute__((address_space(1))) void*)g,
      (__attribute__((address_space(3))) void*)l, 16, 0, 0);
}

// ---------- weight/input conversion ----------
__global__ void k_conv_wsp(const float* __restrict__ W, const float* __restrict__ o,
                           unsigned short* __restrict__ out) {
  size_t i = ((size_t)blockIdx.x * blockDim.x + threadIdx.x) * 4;
  if (i >= (size_t)NH * NH) return;
  float4 w = *reinterpret_cast<const float4*>(W + i);
  int k = (int)(i & (NH - 1));
  float4 ov = *reinterpret_cast<const float4*>(o + k);
  ushort4 r;
  r.x = f2bf(w.x * ov.x); r.y = f2bf(w.y * ov.y);
  r.z = f2bf(w.z * ov.z); r.w = f2bf(w.w * ov.w);
  *reinterpret_cast<ushort4*>(out + i) = r;
}

__global__ void k_conv_pad(const float* __restrict__ in, unsigned short* __restrict__ out,
                           int rows, int kin, int kout) {
  size_t i = (size_t)blockIdx.x * blockDim.x + threadIdx.x;
  if (i >= (size_t)rows * kout) return;
  int r = (int)(i / kout), c = (int)(i % kout);
  out[i] = (c < kin) ? f2bf(in[(size_t)r * kin + c]) : (unsigned short)0;
}

// ---------- pipelined GEMM core: 3-slot ring, vmcnt(6), 1 barrier/K-tile ----------
__device__ __forceinline__ void gemm_core(
    const unsigned short* __restrict__ Ag, const unsigned short* __restrict__ Bg,
    int K, int bm, int bn, unsigned short* lds, f32x4 acc[4][4])
{
  const int t    = threadIdx.x;
  const int lane = t & 63;
  const int wave = t >> 6;
  const int wm   = wave >> 1;          // 0..3 -> 64-row band
  const int wn   = wave & 1;           // 0..1 -> 64-col band
  const int l15  = lane & 15;
  const int lkb  = (lane >> 4) * 16;   // byte offset of k-group within row

  // ---- staging offsets: linear LDS dest chunk c, pre-swizzled global source ----
  unsigned aG[4]; int aL[4];
#pragma unroll
  for (int j = 0; j < 4; ++j) {
    const int c   = j * 512 + t;                 // 16B chunk id in A[256][64]
    const int row = c >> 3;                      // 8 chunks per 128B row
    const int sb  = ((c & 7) * 16) ^ ((row & 7) << 4);
    aL[j] = c * 8;                               // element offset (linear dest)
    aG[j] = (unsigned)((bm + row) * K + (sb >> 1));
  }
  unsigned bG[2]; int bL[2];
#pragma unroll
  for (int j = 0; j < 2; ++j) {
    const int c   = j * 512 + t;                 // chunk id in B[128][64]
    const int row = c >> 3;
    const int sb  = ((c & 7) * 16) ^ ((row & 7) << 4);
    bL[j] = c * 8;
    bG[j] = (unsigned)((bn + row) * K + (sb >> 1));
  }

  // ---- fragment read offsets (elements within slot), swizzled ----
  int aRd[2][4], bRd[2][4];
#pragma unroll
  for (int kk = 0; kk < 2; ++kk)
#pragma unroll
    for (int i = 0; i < 4; ++i) {
      const int ra = wm * 64 + i * 16 + l15;
      aRd[kk][i] = (ra * 128 + ((kk * 64 + lkb) ^ ((ra & 7) << 4))) >> 1;
      const int rb = wn * 64 + i * 16 + l15;
      bRd[kk][i] = (rb * 128 + ((kk * 64 + lkb) ^ ((rb & 7) << 4))) >> 1;
    }

  auto STAGE = [&](int slotIdx, int k0) {
    unsigned short* s = lds + slotIdx * SLOT;
#pragma unroll
    for (int j = 0; j < 4; ++j) async16(Ag + aG[j] + (unsigned)k0, s + aL[j]);
#pragma unroll
    for (int j = 0; j < 2; ++j) async16(Bg + bG[j] + (unsigned)k0, s + ASLOT + bL[j]);
  };

  const int nt = K >> 6;
  // prologue: 2 K-tiles in flight (12 loads)
  STAGE(0, 0);
  if (nt > 1) STAGE(1, 64);

  int s0 = 0;            // kt % 3
  int s2 = 2;            // (kt+2) % 3
  for (int kt = 0; kt < nt; ++kt) {
    __builtin_amdgcn_sched_barrier(0);
    if (kt + 1 < nt) asm volatile("s_waitcnt vmcnt(6)" ::: "memory");
    else             asm volatile("s_waitcnt vmcnt(0)" ::: "memory");
    __builtin_amdgcn_s_barrier();
    __builtin_amdgcn_sched_barrier(0);
    __builtin_amdgcn_s_setprio(1);
    if (kt + 2 < nt) STAGE(s2, (kt + 2) << 6);
    const unsigned short* base = lds + s0 * SLOT;
    // compute region: compiler-scheduled ds_read/MFMA interleave (fine lgkmcnt)
#pragma unroll
    for (int kk = 0; kk < 2; ++kk) {
      bf16x8 af[4], bv[4];
#pragma unroll
      for (int i = 0; i < 4; ++i) af[i] = *reinterpret_cast<const bf16x8*>(base + aRd[kk][i]);
#pragma unroll
      for (int i = 0; i < 4; ++i) bv[i] = *reinterpret_cast<const bf16x8*>(base + ASLOT + bRd[kk][i]);
#pragma unroll
      for (int mi = 0; mi < 4; ++mi)
#pragma unroll
        for (int ni = 0; ni < 4; ++ni)
          acc[mi][ni] = __builtin_amdgcn_mfma_f32_16x16x32_bf16(af[mi], bv[ni], acc[mi][ni], 0, 0, 0);
    }
    __builtin_amdgcn_s_setprio(0);
    s0 = (s0 == 2) ? 0 : s0 + 1;
    s2 = (s2 == 2) ? 0 : s2 + 1;
  }
}

// ---------- recurrent layer GEMM: Y = A @ Wsp'.T + b ; preact + relu->bf16 ----------
__global__ __launch_bounds__(512, 2) void k_gemm_layer(
    const unsigned short* __restrict__ A, const unsigned short* __restrict__ W,
    const float* __restrict__ bias, float* __restrict__ preact,
    unsigned short* __restrict__ Anext)
{
  __shared__ __align__(16) unsigned short lds[3 * SLOT];   // 144 KB
  const int bid = blockIdx.x;                      // 256 blocks
  const int s   = ((bid & 7) << 5) + (bid >> 3);   // XCD-aware bijective swizzle
  const int bm = (s >> 5) * 256;                   // 8 m-blocks
  const int bn = (s & 31) * 128;                   // 32 n-blocks
  f32x4 acc[4][4] = {};
  gemm_core(A, W, NH, bm, bn, lds, acc);

  const int lane = threadIdx.x & 63;
  const int wave = threadIdx.x >> 6;
  const int wm = (wave >> 1) * 64, wn = (wave & 1) * 64;
  const int l15 = lane & 15;
#pragma unroll
  for (int mi = 0; mi < 4; ++mi) {
    const int gm0 = bm + wm + mi * 16 + (lane >> 4) * 4;   // C/D: row=(lane>>4)*4+r
#pragma unroll
    for (int ni = 0; ni < 4; ++ni) {
      const int gn = bn + wn + ni * 16 + l15;              // C/D: col=lane&15
      const float bv = bias[gn];
#pragma unroll
      for (int r = 0; r < 4; ++r) {
        const int gm = gm0 + r;
        const float y = acc[mi][ni][r] + bv;
        if (gm < MB) preact[(size_t)gm * NH + gn] = y;
        Anext[(size_t)gm * NH + gn] = f2bf(y > 0.f ? y : 0.f);
      }
    }
  }
}

// ---------- input GEMM: r = x @ W_in.T + b_in ; split a/b, preact0, relu ----------
__global__ __launch_bounds__(512, 2) void k_gemm_in(
    const unsigned short* __restrict__ X, const unsigned short* __restrict__ W,
    const float* __restrict__ bias, float* __restrict__ preact0,
    unsigned short* __restrict__ A0)
{
  __shared__ __align__(16) unsigned short lds[3 * SLOT];
  const int bid = blockIdx.x;                      // 256 blocks
  const int s   = ((bid & 7) << 5) + (bid >> 3);
  const int bm = (s >> 6) * 256;                   // 4 m-blocks
  const int bn = (s & 63) * 128;                   // 64 n-blocks
  f32x4 acc[4][4] = {};
  gemm_core(X, W, KPAD, bm, bn, lds, acc);

  const int lane = threadIdx.x & 63;
  const int wave = threadIdx.x >> 6;
  const int wm = (wave >> 1) * 64, wn = (wave & 1) * 64;
  const int l15 = lane & 15;
#pragma unroll
  for (int mi = 0; mi < 4; ++mi) {
    const int gm0 = bm + wm + mi * 16 + (lane >> 4) * 4;
#pragma unroll
    for (int ni = 0; ni < 4; ++ni) {
      const int gn = bn + wn + ni * 16 + l15;
      const float bv = bias[gn];
#pragma unroll
      for (int r = 0; r < 4; ++r) {
        const int gm = gm0 + r;
        const float y = acc[mi][ni][r] + bv;
        const unsigned short rl = f2bf(y > 0.f ? y : 0.f);
        if (gn < NH) {                       // "a" stream
          preact0[(size_t)gm * NH + gn] = y;
          A0[(size_t)gm * NH + gn] = rl;
        } else {                             // "b" stream -> rows 1024..2047
          A0[(size_t)(MB + gm) * NH + (gn - NH)] = rl;
        }
      }
    }
  }
}

// ---------- final head: out = (A * of) @ W_f.T + b_f  (N=10) ----------
__global__ void k_final(const unsigned short* __restrict__ A,
                        const float* __restrict__ Wf, const float* __restrict__ of,
                        const float* __restrict__ bf_, float* __restrict__ out)
{
  const int m = blockIdx.x;        // 0..2047
  const int t = threadIdx.x;       // 256
  float accj[NOUT] = {};
  for (int k = t; k < NH; k += 256) {
    const float a = bf2f(A[(size_t)m * NH + k]) * of[k];
#pragma unroll
    for (int j = 0; j < NOUT; ++j) accj[j] += a * Wf[j * NH + k];
  }
  __shared__ float red[4][NOUT];
#pragma unroll
  for (int j = 0; j < NOUT; ++j) {
    float v = accj[j];
    for (int off = 32; off > 0; off >>= 1) v += __shfl_down(v, off);
    if ((t & 63) == 0) red[t >> 6][j] = v;
  }
  __syncthreads();
  if (t < NOUT) {
    const float s = red[0][t] + red[1][t] + red[2][t] + red[3][t] + bf_[t];
    out[(size_t)m * NOUT + t] = s;
  }
}

extern "C" void kernel_launch(void* const* d_in, const int* in_sizes, int n_in,
                              void* d_out, int out_size, void* d_ws, size_t ws_size,
                              hipStream_t stream) {
  const float* x     = (const float*)d_in[0];
  const float* W_in  = (const float*)d_in[1];
  const float* b_in  = (const float*)d_in[2];
  const float* keysp = (const float*)d_in[3];
  const float* W_sp  = (const float*)d_in[4];
  const float* b_sp  = (const float*)d_in[5];
  const float* keyf  = (const float*)d_in[6];
  const float* W_f   = (const float*)d_in[7];
  const float* b_f   = (const float*)d_in[8];

  float* out    = (float*)d_out;
  float* preact = out + (size_t)2 * MB * NOUT;  // 25 x 1024 x 4096

  char* ws = (char*)d_ws;
  unsigned short* Wsp_bf = (unsigned short*)ws;  ws += (size_t)NH * NH * 2;
  unsigned short* A0     = (unsigned short*)ws;  ws += (size_t)M2 * NH * 2;
  unsigned short* A1     = (unsigned short*)ws;  ws += (size_t)M2 * NH * 2;
  unsigned short* Win_bf = (unsigned short*)ws;  ws += (size_t)N_IN * KPAD * 2;
  unsigned short* X_bf   = (unsigned short*)ws;  ws += (size_t)MB * KPAD * 2;

  k_conv_wsp<<<(NH * (size_t)NH / 4 + 255) / 256, 256, 0, stream>>>(W_sp, keysp, Wsp_bf);
  k_conv_pad<<<((size_t)N_IN * KPAD + 255) / 256, 256, 0, stream>>>(W_in, Win_bf, N_IN, DIN, KPAD);
  k_conv_pad<<<((size_t)MB * KPAD + 255) / 256, 256, 0, stream>>>(x, X_bf, MB, DIN, KPAD);

  // input GEMM: M=1024, N=8192, K=832 -> 4*64 = 256 blocks
  k_gemm_in<<<256, 512, 0, stream>>>(X_bf, Win_bf, b_in, preact, A0);

  // 24 recurrent layers: M=2048, N=4096, K=4096 -> 8*32 = 256 blocks
  unsigned short* Ain = A0;
  unsigned short* Aout = A1;
  for (int tlay = 0; tlay < NLAYERS; ++tlay) {
    float* pre = preact + (size_t)(tlay + 1) * MB * NH;
    k_gemm_layer<<<256, 512, 0, stream>>>(Ain, Wsp_bf, b_sp, pre, Aout);
    unsigned short* tmp = Ain; Ain = Aout; Aout = tmp;
  }

  k_final<<<M2, 256, 0, stream>>>(Ain, W_f, keyf, b_f, out);
}